// Round 6
// baseline (230.438 us; speedup 1.0000x reference)
//
#include <hip/hip_runtime.h>

#define T_TOK 16384
#define H_DIM 2048
#define E_EXP 64
#define AUX_COEFF 0.01f
#define Z_COEFF 0.001f

#define TOKB 16               // tokens per block
#define NBLK (T_TOK / TOKB)   // 1024 blocks
#define BLOCK 256             // 4 waves; wave wv = K-quarter
#define CHUNKS 16             // K chunks of 32 per quarter (4*16*32 = 2048)

// d_ws: wpk uint4[64*8*64] = 512KB; then accb floats:
//   sp[32][64] @ 0, cn[32][64] @ 2048, z[64] @ 4096  -> 4160 floats
#define WPK_U4 (64 * 8 * 64)
#define ACC_OFF ((size_t)WPK_U4 * 16)
#define ACC_N 4160

typedef __attribute__((ext_vector_type(8))) short short8;
typedef __attribute__((ext_vector_type(4))) float f32x4;

__device__ __forceinline__ unsigned bf16rne(float f) {
  unsigned u = __float_as_uint(f);
  return (u + 0x7fffu + ((u >> 16) & 1u)) >> 16;
}

// ===== NUMERICS FROZEN (round-4 proven pass; near-tie top_idx sensitivity) ==
// 3-way RNE bf16 split of 8 floats: x ~= ah + am + al. Do NOT alter: any
// low-order-bit change re-rolls tie resolution vs the reference (round 5
// failed with a MORE accurate split). Same for MFMA order below.
__device__ __forceinline__ void cvt3(const f32x4 a, const f32x4 b, short8& ah,
                                     short8& am, short8& al) {
  float v[8] = {a.x, a.y, a.z, a.w, b.x, b.y, b.z, b.w};
#pragma unroll
  for (int j = 0; j < 8; ++j) {
    unsigned h = bf16rne(v[j]);
    float r1 = v[j] - __uint_as_float(h << 16);
    unsigned m = bf16rne(r1);
    float r2 = r1 - __uint_as_float(m << 16);
    unsigned l = bf16rne(r2);
    ah[j] = (short)h;
    am[j] = (short)m;
    al[j] = (short)l;
  }
}

// ---- pack W -> bf16 hi/lo B-fragments (RNE 2-way); also zero accumulators ----
// lane l holds B[k = c*32 + (l>>4)*8 + j][e = n*16 + (l&15)], j = 0..7
__global__ __launch_bounds__(256) void pack_w(const float* __restrict__ w,
                                              uint4* __restrict__ wpk,
                                              float* __restrict__ accb) {
  const int gid = blockIdx.x * 256 + threadIdx.x;
  if (gid < ACC_N) accb[gid] = 0.f;
  const int c = blockIdx.x;  // 0..63
  const int lane = threadIdx.x & 63;
  const int n = threadIdx.x >> 6;
  const int g = lane >> 4;
  const int e = n * 16 + (lane & 15);
  unsigned hi[8], lo[8];
#pragma unroll
  for (int j = 0; j < 8; ++j) {
    float v = w[(size_t)(c * 32 + g * 8 + j) * E_EXP + e];
    unsigned h = bf16rne(v);
    hi[j] = h;
    lo[j] = bf16rne(v - __uint_as_float(h << 16));
  }
  uint4 H, L;
  H.x = hi[0] | (hi[1] << 16); H.y = hi[2] | (hi[3] << 16);
  H.z = hi[4] | (hi[5] << 16); H.w = hi[6] | (hi[7] << 16);
  L.x = lo[0] | (lo[1] << 16); L.y = lo[2] | (lo[3] << 16);
  L.z = lo[4] | (lo[5] << 16); L.w = lo[6] | (lo[7] << 16);
  wpk[((size_t)c * 8 + n * 2) * 64 + lane] = H;
  wpk[((size_t)c * 8 + n * 2 + 1) * 64 + lane] = L;
}

#define MFMA __builtin_amdgcn_mfma_f32_16x16x32_bf16

__global__ __launch_bounds__(BLOCK, 2) void router_main(
    const float* __restrict__ x, const uint4* __restrict__ wpk,
    float* __restrict__ out, float* __restrict__ accb) {
  __shared__ float ldst[4][TOKB][E_EXP];  // per-kq partial logits, 16KB
  __shared__ float rsp[4][64], rcn[4][64], rz[4];

  const int tid = threadIdx.x, lane = tid & 63, wv = tid >> 6;
  const int r = lane & 15, g = lane >> 4;
  const int t0 = blockIdx.x * TOKB;

  // A source: token t0+r, K-quarter wv, fragment k-offset g*8 (+32 per chunk)
  const float* xb = x + (size_t)(t0 + r) * H_DIM + wv * 512 + g * 8;
  // B source: chunk stride 512 uint4; per-lane offset `lane`
  const uint4* wb = wpk + (size_t)(wv * 16) * 512 + lane;

  f32x4 acc[4];
#pragma unroll
  for (int n = 0; n < 4; ++n) acc[n] = f32x4{0.f, 0.f, 0.f, 0.f};

  // 4-deep x prefetch ring (register slots), 2-deep B double-buffer
  f32x4 xs[4][2];
  uint4 Bb[2][8];
#pragma unroll
  for (int s = 0; s < 4; ++s) {
    xs[s][0] = *(const f32x4*)(xb + s * 32);
    xs[s][1] = *(const f32x4*)(xb + s * 32 + 4);
  }
#pragma unroll
  for (int f = 0; f < 8; ++f) Bb[0][f] = wb[f * 64];
#pragma unroll
  for (int f = 0; f < 8; ++f) Bb[1][f] = wb[512 + f * 64];

#pragma unroll
  for (int c = 0; c < CHUNKS; ++c) {
    // 1) convert current x slot (FROZEN: RNE 3-way split)
    short8 ah, am, al;
    cvt3(xs[c & 3][0], xs[c & 3][1], ah, am, al);
    // 2) 20 MFMAs (FROZEN order: small terms first)
#pragma unroll
    for (int n = 0; n < 4; ++n) {
      short8 bh = __builtin_bit_cast(short8, Bb[c & 1][n * 2]);
      short8 bl = __builtin_bit_cast(short8, Bb[c & 1][n * 2 + 1]);
      acc[n] = MFMA(al, bh, acc[n], 0, 0, 0);
      acc[n] = MFMA(am, bl, acc[n], 0, 0, 0);
      acc[n] = MFMA(am, bh, acc[n], 0, 0, 0);
      acc[n] = MFMA(ah, bl, acc[n], 0, 0, 0);
      acc[n] = MFMA(ah, bh, acc[n], 0, 0, 0);
    }
    // 3) refill B (c+2) BEFORE x refill: keeps fast L2 B-loads ahead of slow
    //    HBM x-loads in the in-order vmcnt FIFO (B-wait won't drain x)
    if (c + 2 < CHUNKS) {
#pragma unroll
      for (int f = 0; f < 8; ++f) Bb[c & 1][f] = wb[(c + 2) * 512 + f * 64];
    }
    // 4) refill x slot with chunk c+4 (1280cy cover >= ~900cy HBM latency)
    if (c + 4 < CHUNKS) {
      xs[c & 3][0] = *(const f32x4*)(xb + (c + 4) * 32);
      xs[c & 3][1] = *(const f32x4*)(xb + (c + 4) * 32 + 4);
    }
  }

  // C-frag -> LDS: D row (token) = g*4+q, D col (expert) = n*16+r  [m89 layout]
#pragma unroll
  for (int n = 0; n < 4; ++n)
#pragma unroll
    for (int q = 0; q < 4; ++q)
      ldst[wv][g * 4 + q][n * 16 + r] = acc[n][q];
  __syncthreads();

  // ---- epilogue: wave wv owns local tokens 4wv..4wv+3; lane == expert ----
  float sumprob = 0.f, cnt = 0.f, lse2 = 0.f;
#pragma unroll
  for (int i = 0; i < 4; ++i) {
    const int tl = wv * 4 + i;
    const float v = ldst[0][tl][lane] + ldst[1][tl][lane] +
                    ldst[2][tl][lane] + ldst[3][tl][lane];
    float m = v;
#pragma unroll
    for (int d = 1; d < 64; d <<= 1) m = fmaxf(m, __shfl_xor(m, d));
    const float e = expf(v - m);
    float s = e;
#pragma unroll
    for (int d = 1; d < 64; d <<= 1) s += __shfl_xor(s, d);
    sumprob += e / s;
    const float lse = m + logf(s);
    lse2 += lse * lse;

    // top-2 on logits (softmax-monotone); ties -> lowest index (jax)
    float v1 = v; int i1 = lane;
#pragma unroll
    for (int d = 1; d < 64; d <<= 1) {
      float ov = __shfl_xor(v1, d); int oi = __shfl_xor(i1, d);
      if (ov > v1 || (ov == v1 && oi < i1)) { v1 = ov; i1 = oi; }
    }
    float vx = (lane == i1) ? -__FLT_MAX__ : v;
    float v2 = vx; int i2 = lane;
#pragma unroll
    for (int d = 1; d < 64; d <<= 1) {
      float ov = __shfl_xor(v2, d); int oi = __shfl_xor(i2, d);
      if (ov > v2 || (ov == v2 && oi < i2)) { v2 = ov; i2 = oi; }
    }
    if (lane == 0) {
      const int t = t0 + tl;
      out[t * 2] = expf(v1 - m) / s;
      out[t * 2 + 1] = expf(v2 - m) / s;
      out[2 * T_TOK + t * 2] = (float)i1;
      out[2 * T_TOK + t * 2 + 1] = (float)i2;
    }
    cnt += (lane == i1 || lane == i2) ? 1.f : 0.f;
  }

  rsp[wv][lane] = sumprob;
  rcn[wv][lane] = cnt;
  if (lane == 0) rz[wv] = lse2;
  __syncthreads();
  if (wv == 0) {
    const float sp4 = rsp[0][lane] + rsp[1][lane] + rsp[2][lane] + rsp[3][lane];
    const float cn4 = rcn[0][lane] + rcn[1][lane] + rcn[2][lane] + rcn[3][lane];
    const int slot = blockIdx.x & 31;
    atomicAdd(&accb[slot * 64 + lane], sp4);
    atomicAdd(&accb[2048 + slot * 64 + lane], cn4);
    if (lane == 0)
      atomicAdd(&accb[4096 + (blockIdx.x & 63)],
                rz[0] + rz[1] + rz[2] + rz[3]);
  }
}

__global__ __launch_bounds__(64) void router_reduce(
    const float* __restrict__ accb, float* __restrict__ out) {
  const int lane = threadIdx.x;
  float SP = 0.f, CN = 0.f;
#pragma unroll
  for (int s = 0; s < 32; ++s) {
    SP += accb[s * 64 + lane];
    CN += accb[2048 + s * 64 + lane];
  }
  float prod = SP * CN;
  float Z = accb[4096 + lane];
#pragma unroll
  for (int d = 1; d < 64; d <<= 1) {
    prod += __shfl_xor(prod, d);
    Z += __shfl_xor(Z, d);
  }
  if (lane == 0) {
    const float Tf = (float)T_TOK;
    out[4 * T_TOK] = AUX_COEFF * ((float)E_EXP / 2.0f) * prod / (Tf * Tf);
    out[4 * T_TOK + 1] = Z_COEFF * Z / Tf;
  }
}

extern "C" void kernel_launch(void* const* d_in, const int* in_sizes, int n_in,
                              void* d_out, int out_size, void* d_ws,
                              size_t ws_size, hipStream_t stream) {
  const float* x = (const float*)d_in[0];
  const float* w = (const float*)d_in[1];
  float* out = (float*)d_out;
  uint4* wpk = (uint4*)d_ws;
  float* accb = (float*)((char*)d_ws + ACC_OFF);

  pack_w<<<64, 256, 0, stream>>>(w, wpk, accb);
  router_main<<<NBLK, BLOCK, 0, stream>>>(x, wpk, out, accb);
  router_reduce<<<1, 64, 0, stream>>>(accb, out);
}

// Round 7
// 224.416 us; speedup vs baseline: 1.0268x; 1.0268x over previous
//
#include <hip/hip_runtime.h>

#define T_TOK 16384
#define H_DIM 2048
#define E_EXP 64
#define AUX_COEFF 0.01f
#define Z_COEFF 0.001f

#define TOKB 32               // tokens per block (2 tiles of 16 per wave)
#define NBLK (T_TOK / TOKB)   // 512 blocks = 2 per CU
#define BLOCK 256             // 4 waves; wave wv = K-quarter (FROZEN structure)
#define CHUNKS 16             // K chunks of 32 per quarter

// d_ws: wpk uint4[64*8*64] = 512KB; then accb floats:
//   sp[32][64] @ 0, cn[32][64] @ 2048, z[64] @ 4096  -> 4160 floats
#define WPK_U4 (64 * 8 * 64)
#define ACC_OFF ((size_t)WPK_U4 * 16)
#define ACC_N 4160

typedef __attribute__((ext_vector_type(8))) short short8;
typedef __attribute__((ext_vector_type(4))) float f32x4;

__device__ __forceinline__ unsigned bf16rne(float f) {
  unsigned u = __float_as_uint(f);
  return (u + 0x7fffu + ((u >> 16) & 1u)) >> 16;
}

// ===== NUMERICS FROZEN (round-4/6 proven pass; near-tie top_idx risk) ======
// RNE 3-way bf16 split. Do NOT alter any arithmetic here or in the MFMA
// order below: round 5 failed from a (more accurate!) split变 change.
__device__ __forceinline__ void cvt3(const f32x4 a, const f32x4 b, short8& ah,
                                     short8& am, short8& al) {
  float v[8] = {a.x, a.y, a.z, a.w, b.x, b.y, b.z, b.w};
#pragma unroll
  for (int j = 0; j < 8; ++j) {
    unsigned h = bf16rne(v[j]);
    float r1 = v[j] - __uint_as_float(h << 16);
    unsigned m = bf16rne(r1);
    float r2 = r1 - __uint_as_float(m << 16);
    unsigned l = bf16rne(r2);
    ah[j] = (short)h;
    am[j] = (short)m;
    al[j] = (short)l;
  }
}

// ---- pack W -> bf16 hi/lo B-fragments (FROZEN); also zero accumulators ----
// lane l holds B[k = c*32 + (l>>4)*8 + j][e = n*16 + (l&15)], j = 0..7
__global__ __launch_bounds__(256) void pack_w(const float* __restrict__ w,
                                              uint4* __restrict__ wpk,
                                              float* __restrict__ accb) {
  const int gid = blockIdx.x * 256 + threadIdx.x;
  if (gid < ACC_N) accb[gid] = 0.f;
  const int c = blockIdx.x;  // 0..63
  const int lane = threadIdx.x & 63;
  const int n = threadIdx.x >> 6;
  const int g = lane >> 4;
  const int e = n * 16 + (lane & 15);
  unsigned hi[8], lo[8];
#pragma unroll
  for (int j = 0; j < 8; ++j) {
    float v = w[(size_t)(c * 32 + g * 8 + j) * E_EXP + e];
    unsigned h = bf16rne(v);
    hi[j] = h;
    lo[j] = bf16rne(v - __uint_as_float(h << 16));
  }
  uint4 H, L;
  H.x = hi[0] | (hi[1] << 16); H.y = hi[2] | (hi[3] << 16);
  H.z = hi[4] | (hi[5] << 16); H.w = hi[6] | (hi[7] << 16);
  L.x = lo[0] | (lo[1] << 16); L.y = lo[2] | (lo[3] << 16);
  L.z = lo[4] | (lo[5] << 16); L.w = lo[6] | (lo[7] << 16);
  wpk[((size_t)c * 8 + n * 2) * 64 + lane] = H;
  wpk[((size_t)c * 8 + n * 2 + 1) * 64 + lane] = L;
}

#define MFMA __builtin_amdgcn_mfma_f32_16x16x32_bf16
#define BC(u) __builtin_bit_cast(short8, u)

// One K-chunk, c MUST be a literal constant: all register-array indices fold
// to compile-time constants (rule #20: runtime-indexed arrays -> scratch;
// round 6's VGPR_Count=28 showed the old c-loop did exactly that).
// Arithmetic chain per accumulator is FROZEN (identical to round 4/6).
#define CHUNK(c)                                                          \
  do {                                                                    \
    short8 ah0, am0, al0, ah1, am1, al1;                                  \
    cvt3(xs[(c) & 1][0][0], xs[(c) & 1][0][1], ah0, am0, al0);            \
    cvt3(xs[(c) & 1][1][0], xs[(c) & 1][1][1], ah1, am1, al1);            \
    _Pragma("unroll") for (int n = 0; n < 4; ++n) {                       \
      const short8 bh = BC(Bb[(c) & 1][n * 2]);                           \
      const short8 bl = BC(Bb[(c) & 1][n * 2 + 1]);                       \
      acc[0][n] = MFMA(al0, bh, acc[0][n], 0, 0, 0);                      \
      acc[0][n] = MFMA(am0, bl, acc[0][n], 0, 0, 0);                      \
      acc[0][n] = MFMA(am0, bh, acc[0][n], 0, 0, 0);                      \
      acc[0][n] = MFMA(ah0, bl, acc[0][n], 0, 0, 0);                      \
      acc[0][n] = MFMA(ah0, bh, acc[0][n], 0, 0, 0);                      \
      acc[1][n] = MFMA(al1, bh, acc[1][n], 0, 0, 0);                      \
      acc[1][n] = MFMA(am1, bl, acc[1][n], 0, 0, 0);                      \
      acc[1][n] = MFMA(am1, bh, acc[1][n], 0, 0, 0);                      \
      acc[1][n] = MFMA(ah1, bl, acc[1][n], 0, 0, 0);                      \
      acc[1][n] = MFMA(ah1, bh, acc[1][n], 0, 0, 0);                      \
    }                                                                     \
    if ((c) + 2 < CHUNKS) {                                               \
      _Pragma("unroll") for (int f = 0; f < 8; ++f)                       \
          Bb[(c) & 1][f] = wb[((c) + 2) * 512 + f * 64];                  \
      xs[(c) & 1][0][0] = *(const f32x4*)(xb0 + ((c) + 2) * 32);          \
      xs[(c) & 1][0][1] = *(const f32x4*)(xb0 + ((c) + 2) * 32 + 4);      \
      xs[(c) & 1][1][0] = *(const f32x4*)(xb1 + ((c) + 2) * 32);          \
      xs[(c) & 1][1][1] = *(const f32x4*)(xb1 + ((c) + 2) * 32 + 4);      \
    }                                                                     \
  } while (0)

__global__ __launch_bounds__(BLOCK, 2) void router_main(
    const float* __restrict__ x, const uint4* __restrict__ wpk,
    float* __restrict__ out, float* __restrict__ accb) {
  __shared__ float ldst[4][TOKB][E_EXP];  // per-quarter partial logits, 32KB
  __shared__ float rsp[4][64], rcn[4][64], rz[4];

  const int tid = threadIdx.x, lane = tid & 63, wv = tid >> 6;
  const int r = lane & 15, g = lane >> 4;
  const int t0 = blockIdx.x * TOKB;

  // A sources: tile0 = tokens t0+r, tile1 = tokens t0+16+r; K-quarter wv
  const float* xb0 = x + (size_t)(t0 + r) * H_DIM + wv * 512 + g * 8;
  const float* xb1 = xb0 + (size_t)16 * H_DIM;
  // B source: chunk stride 512 uint4; per-lane offset `lane`
  const uint4* wb = wpk + (size_t)(wv * 16) * 512 + lane;

  f32x4 acc[2][4];
#pragma unroll
  for (int t = 0; t < 2; ++t)
#pragma unroll
    for (int n = 0; n < 4; ++n) acc[t][n] = f32x4{0.f, 0.f, 0.f, 0.f};

  // 2-slot x ring (2 tiles x 2 vec4) + 2-slot B double buffer, distance 2
  f32x4 xs[2][2][2];
  uint4 Bb[2][8];
#pragma unroll
  for (int s = 0; s < 2; ++s) {
    xs[s][0][0] = *(const f32x4*)(xb0 + s * 32);
    xs[s][0][1] = *(const f32x4*)(xb0 + s * 32 + 4);
    xs[s][1][0] = *(const f32x4*)(xb1 + s * 32);
    xs[s][1][1] = *(const f32x4*)(xb1 + s * 32 + 4);
  }
#pragma unroll
  for (int f = 0; f < 8; ++f) Bb[0][f] = wb[f * 64];
#pragma unroll
  for (int f = 0; f < 8; ++f) Bb[1][f] = wb[512 + f * 64];

  CHUNK(0);  CHUNK(1);  CHUNK(2);  CHUNK(3);
  CHUNK(4);  CHUNK(5);  CHUNK(6);  CHUNK(7);
  CHUNK(8);  CHUNK(9);  CHUNK(10); CHUNK(11);
  CHUNK(12); CHUNK(13); CHUNK(14); CHUNK(15);

  // C-frag -> LDS: D row (token) = g*4+q, D col (expert) = n*16+r  [m89]
#pragma unroll
  for (int t = 0; t < 2; ++t)
#pragma unroll
    for (int n = 0; n < 4; ++n)
#pragma unroll
      for (int q = 0; q < 4; ++q)
        ldst[wv][t * 16 + g * 4 + q][n * 16 + r] = acc[t][n][q];
  __syncthreads();

  // ---- epilogue: wave wv owns local tokens 8wv..8wv+7; lane == expert ----
  // (FROZEN: quarter-sum order wv0+wv1+wv2+wv3, softmax/top-2 sequence)
  float sumprob = 0.f, cnt = 0.f, lse2 = 0.f;
#pragma unroll
  for (int i = 0; i < 8; ++i) {
    const int tl = wv * 8 + i;
    const float v = ldst[0][tl][lane] + ldst[1][tl][lane] +
                    ldst[2][tl][lane] + ldst[3][tl][lane];
    float m = v;
#pragma unroll
    for (int d = 1; d < 64; d <<= 1) m = fmaxf(m, __shfl_xor(m, d));
    const float e = expf(v - m);
    float s = e;
#pragma unroll
    for (int d = 1; d < 64; d <<= 1) s += __shfl_xor(s, d);
    sumprob += e / s;
    const float lse = m + logf(s);
    lse2 += lse * lse;

    // top-2 on logits (softmax-monotone); ties -> lowest index (jax)
    float v1 = v; int i1 = lane;
#pragma unroll
    for (int d = 1; d < 64; d <<= 1) {
      float ov = __shfl_xor(v1, d); int oi = __shfl_xor(i1, d);
      if (ov > v1 || (ov == v1 && oi < i1)) { v1 = ov; i1 = oi; }
    }
    float vx = (lane == i1) ? -__FLT_MAX__ : v;
    float v2 = vx; int i2 = lane;
#pragma unroll
    for (int d = 1; d < 64; d <<= 1) {
      float ov = __shfl_xor(v2, d); int oi = __shfl_xor(i2, d);
      if (ov > v2 || (ov == v2 && oi < i2)) { v2 = ov; i2 = oi; }
    }
    if (lane == 0) {
      const int t = t0 + tl;
      out[t * 2] = expf(v1 - m) / s;
      out[t * 2 + 1] = expf(v2 - m) / s;
      out[2 * T_TOK + t * 2] = (float)i1;
      out[2 * T_TOK + t * 2 + 1] = (float)i2;
    }
    cnt += (lane == i1 || lane == i2) ? 1.f : 0.f;
  }

  rsp[wv][lane] = sumprob;
  rcn[wv][lane] = cnt;
  if (lane == 0) rz[wv] = lse2;
  __syncthreads();
  if (wv == 0) {
    const float sp4 = rsp[0][lane] + rsp[1][lane] + rsp[2][lane] + rsp[3][lane];
    const float cn4 = rcn[0][lane] + rcn[1][lane] + rcn[2][lane] + rcn[3][lane];
    const int slot = blockIdx.x & 31;
    atomicAdd(&accb[slot * 64 + lane], sp4);
    atomicAdd(&accb[2048 + slot * 64 + lane], cn4);
    if (lane == 0)
      atomicAdd(&accb[4096 + (blockIdx.x & 63)],
                rz[0] + rz[1] + rz[2] + rz[3]);
  }
}

__global__ __launch_bounds__(64) void router_reduce(
    const float* __restrict__ accb, float* __restrict__ out) {
  const int lane = threadIdx.x;
  float SP = 0.f, CN = 0.f;
#pragma unroll
  for (int s = 0; s < 32; ++s) {
    SP += accb[s * 64 + lane];
    CN += accb[2048 + s * 64 + lane];
  }
  float prod = SP * CN;
  float Z = accb[4096 + lane];
#pragma unroll
  for (int d = 1; d < 64; d <<= 1) {
    prod += __shfl_xor(prod, d);
    Z += __shfl_xor(Z, d);
  }
  if (lane == 0) {
    const float Tf = (float)T_TOK;
    out[4 * T_TOK] = AUX_COEFF * ((float)E_EXP / 2.0f) * prod / (Tf * Tf);
    out[4 * T_TOK + 1] = Z_COEFF * Z / Tf;
  }
}

extern "C" void kernel_launch(void* const* d_in, const int* in_sizes, int n_in,
                              void* d_out, int out_size, void* d_ws,
                              size_t ws_size, hipStream_t stream) {
  const float* x = (const float*)d_in[0];
  const float* w = (const float*)d_in[1];
  float* out = (float*)d_out;
  uint4* wpk = (uint4*)d_ws;
  float* accb = (float*)((char*)d_ws + ACC_OFF);

  pack_w<<<64, 256, 0, stream>>>(w, wpk, accb);
  router_main<<<NBLK, BLOCK, 0, stream>>>(x, wpk, out, accb);
  router_reduce<<<1, 64, 0, stream>>>(accb, out);
}